// Round 1
// baseline (738.151 us; speedup 1.0000x reference)
//
#include <hip/hip_runtime.h>
#include <hip/hip_bf16.h>

typedef unsigned short u16;
typedef __bf16 bf16x8 __attribute__((ext_vector_type(8)));
typedef float f32x4 __attribute__((ext_vector_type(4)));

__device__ __forceinline__ float bf2f(u16 u) {
  union { unsigned int i; float f; } v; v.i = ((unsigned int)u) << 16; return v.f;
}
__device__ __forceinline__ u16 f2bf(float f) {
  union { float f; unsigned int i; } v; v.f = f;
  unsigned int r = v.i + 0x7fffu + ((v.i >> 16) & 1u);
  return (u16)(r >> 16);
}

__device__ __forceinline__ void async_load16(void* lds, const void* g) {
  __builtin_amdgcn_global_load_lds((const __attribute__((address_space(1))) void*)g,
                                   (__attribute__((address_space(3))) void*)lds, 16, 0, 0);
}

// ---------------- fp32 -> bf16 convert ----------------
__global__ void f32_to_bf16(const float* __restrict__ src, u16* __restrict__ dst, int n) {
  int idx = blockIdx.x * blockDim.x + threadIdx.x;
  int stride = gridDim.x * blockDim.x * 4;
  for (int i = idx * 4; i < n; i += stride) {
    float4 v = *(const float4*)(src + i);
    ushort4 o;
    o.x = f2bf(v.x); o.y = f2bf(v.y); o.z = f2bf(v.z); o.w = f2bf(v.w);
    *(ushort4*)(dst + i) = o;
  }
}

// ---------------- GEMM: C[M,N] = A[M,K] * B[N,K]^T (m97-style 128x128 tile) ----------------
template <int OUT_F32>
__global__ void gemm_bt(const u16* __restrict__ A, const u16* __restrict__ Bm,
                        void* __restrict__ C, int M, int N, int K) {
  __shared__ __align__(16) u16 sA[128 * 32];
  __shared__ __align__(16) u16 sB[128 * 32];
  const int nTn = N >> 7;
  const int nwg = gridDim.x;
  const int cpx = nwg >> 3;
  int id = blockIdx.x;
  int swz = (id & 7) * cpx + (id >> 3);   // XCD-chunked (nwg % 8 == 0)
  int tm = swz / nTn, tn = swz % nTn;
  const int t = threadIdx.x;
  const int w = t >> 6, l = t & 63;
  const int wr = w >> 1, wc = w & 1;
  const int lr = l & 15, lh = l >> 4;
  const size_t row0 = (size_t)tm * 128, col0 = (size_t)tn * 128;

  f32x4 zero = {0.f, 0.f, 0.f, 0.f};
  f32x4 acc[4][4];
#pragma unroll
  for (int i = 0; i < 4; ++i)
#pragma unroll
    for (int j = 0; j < 4; ++j) acc[i][j] = zero;

  const u16* Ag = A + row0 * K;
  const u16* Bg = Bm + col0 * K;

  for (int k0 = 0; k0 < K; k0 += 32) {
#pragma unroll
    for (int i = 0; i < 2; ++i) {
      int c = i * 256 + t;
      int r = c >> 2, kk = (c & 3) << 3;
      async_load16(sA + (((size_t)i * 256 + w * 64) << 3), Ag + (size_t)r * K + k0 + kk);
      async_load16(sB + (((size_t)i * 256 + w * 64) << 3), Bg + (size_t)r * K + k0 + kk);
    }
    __syncthreads();  // drains vmcnt: global_load_lds data landed
    bf16x8 af[4], bfr[4];
#pragma unroll
    for (int mi = 0; mi < 4; ++mi)
      af[mi] = *reinterpret_cast<const bf16x8*>(sA + (wr * 64 + mi * 16 + lr) * 32 + lh * 8);
#pragma unroll
    for (int ni = 0; ni < 4; ++ni)
      bfr[ni] = *reinterpret_cast<const bf16x8*>(sB + (wc * 64 + ni * 16 + lr) * 32 + lh * 8);
#pragma unroll
    for (int mi = 0; mi < 4; ++mi)
#pragma unroll
      for (int ni = 0; ni < 4; ++ni)
        acc[mi][ni] = __builtin_amdgcn_mfma_f32_16x16x32_bf16(af[mi], bfr[ni], acc[mi][ni], 0, 0, 0);
    __syncthreads();
  }

#pragma unroll
  for (int mi = 0; mi < 4; ++mi)
#pragma unroll
    for (int ni = 0; ni < 4; ++ni)
#pragma unroll
      for (int r = 0; r < 4; ++r) {
        size_t row = row0 + wr * 64 + mi * 16 + lh * 4 + r;
        size_t col = col0 + wc * 64 + ni * 16 + lr;
        float v = acc[mi][ni][r];
        if (OUT_F32)
          ((float*)C)[row * N + col] = v;
        else
          ((u16*)C)[row * N + col] = f2bf(v);
      }
}

// ---------------- RoPE (in-place on bf16 Q or K), [4096 rows][2048] ----------------
__global__ void rope_kernel(u16* __restrict__ q, const float* __restrict__ cosb,
                            const float* __restrict__ sinb) {
  int tid = blockIdx.x * blockDim.x + threadIdx.x;  // 4096*16*16 threads
  int p = tid & 15;
  int h = (tid >> 4) & 15;
  int row = tid >> 8;
  int s = row & 2047;
  int d0 = p << 2;
  size_t base = (size_t)row * 2048 + h * 128;
  u16* q0p = q + base + d0;
  u16* q1p = q + base + 64 + d0;
  ushort4 a = *(ushort4*)q0p, b = *(ushort4*)q1p;
  float4 c0 = *(const float4*)(cosb + s * 128 + d0);
  float4 c1 = *(const float4*)(cosb + s * 128 + 64 + d0);
  float4 s0 = *(const float4*)(sinb + s * 128 + d0);
  float4 s1 = *(const float4*)(sinb + s * 128 + 64 + d0);
  float a0 = bf2f(a.x), a1 = bf2f(a.y), a2 = bf2f(a.z), a3 = bf2f(a.w);
  float b0 = bf2f(b.x), b1 = bf2f(b.y), b2 = bf2f(b.z), b3 = bf2f(b.w);
  ushort4 o0, o1;
  o0.x = f2bf(a0 * c0.x - b0 * s0.x);
  o0.y = f2bf(a1 * c0.y - b1 * s0.y);
  o0.z = f2bf(a2 * c0.z - b2 * s0.z);
  o0.w = f2bf(a3 * c0.w - b3 * s0.w);
  o1.x = f2bf(b0 * c1.x + a0 * s1.x);
  o1.y = f2bf(b1 * c1.y + a1 * s1.y);
  o1.z = f2bf(b2 * c1.z + a2 * s1.z);
  o1.w = f2bf(b3 * c1.w + a3 * s1.w);
  *(ushort4*)q0p = o0;
  *(ushort4*)q1p = o1;
}

// ---------------- Flash attention ----------------
// Q,K: [B*S][D] bf16 (roped). VT: [D][B*S] bf16. O: [B*S][D] bf16.
// grid 1024 = 32 bh * 32 qtiles; block 256 (4 waves x 16 q rows); KV tile = 64.
__global__ __launch_bounds__(256)
void attn_kernel(const u16* __restrict__ Qb, const u16* __restrict__ Kb,
                 const u16* __restrict__ VT, u16* __restrict__ Ob) {
  __shared__ __align__(16) u16 Plds[4][16][72];  // padded: stride 144B -> ~2-way conflicts
  int id = blockIdx.x;
  int swz = (id & 7) * 128 + (id >> 3);  // XCD-chunked: 4 bh per XCD chunk -> KV L2-resident
  int bh = swz >> 5;
  int qt = swz & 31;
  int b = bh >> 4, h = bh & 15;
  int t = threadIdx.x, w = t >> 6, l = t & 63;
  int lr = l & 15, lh = l >> 4;
  int s0 = qt * 64 + w * 16;

  size_t qrow = (size_t)(b * 2048 + s0 + lr) * 2048 + h * 128;
  bf16x8 aq[4];
#pragma unroll
  for (int c = 0; c < 4; ++c)
    aq[c] = *reinterpret_cast<const bf16x8*>(Qb + qrow + c * 32 + lh * 8);

  f32x4 zero = {0.f, 0.f, 0.f, 0.f};
  f32x4 acc_o[8];
#pragma unroll
  for (int d = 0; d < 8; ++d) acc_o[d] = zero;
  float m_row[4] = {-1e30f, -1e30f, -1e30f, -1e30f};
  float l_row[4] = {0.f, 0.f, 0.f, 0.f};
  const float sc = 0.08838834764831845f;  // 1/sqrt(128)

  const u16* Kbase = Kb + (size_t)(b * 2048) * 2048 + h * 128;
  const u16* Vbase = VT + (size_t)(h * 128) * 4096 + b * 2048;

  for (int kt = 0; kt < 32; ++kt) {
    f32x4 sacc[4];
#pragma unroll
    for (int g = 0; g < 4; ++g) sacc[g] = zero;
#pragma unroll
    for (int g = 0; g < 4; ++g) {
      size_t krow = (size_t)(kt * 64 + g * 16 + lr) * 2048;
#pragma unroll
      for (int c = 0; c < 4; ++c) {
        bf16x8 bk = *reinterpret_cast<const bf16x8*>(Kbase + krow + c * 32 + lh * 8);
        sacc[g] = __builtin_amdgcn_mfma_f32_16x16x32_bf16(aq[c], bk, sacc[g], 0, 0, 0);
      }
    }
    // online softmax (rows live on 16-lane groups; q = lh*4 + r)
    float pv[4][4];
    float alpha[4];
#pragma unroll
    for (int r = 0; r < 4; ++r) {
      float mx = fmaxf(fmaxf(sacc[0][r], sacc[1][r]), fmaxf(sacc[2][r], sacc[3][r]));
      mx *= sc;
#pragma unroll
      for (int msk = 1; msk < 16; msk <<= 1) mx = fmaxf(mx, __shfl_xor(mx, msk));
      float mn = fmaxf(m_row[r], mx);
      alpha[r] = __expf(m_row[r] - mn);
      m_row[r] = mn;
      float rs = 0.f;
#pragma unroll
      for (int g = 0; g < 4; ++g) {
        float e = __expf(sacc[g][r] * sc - mn);
        pv[g][r] = e;
        rs += e;
      }
#pragma unroll
      for (int msk = 1; msk < 16; msk <<= 1) rs += __shfl_xor(rs, msk);
      l_row[r] = l_row[r] * alpha[r] + rs;
    }
#pragma unroll
    for (int d = 0; d < 8; ++d) {
      f32x4 t4 = acc_o[d];
      t4[0] *= alpha[0]; t4[1] *= alpha[1]; t4[2] *= alpha[2]; t4[3] *= alpha[3];
      acc_o[d] = t4;
    }
    // P -> LDS (per-wave region), re-layout for PV A-operand
#pragma unroll
    for (int g = 0; g < 4; ++g)
#pragma unroll
      for (int r = 0; r < 4; ++r)
        Plds[w][lh * 4 + r][g * 16 + lr] = f2bf(pv[g][r]);
    asm volatile("s_waitcnt lgkmcnt(0)" ::: "memory");
    bf16x8 ap[2];
#pragma unroll
    for (int c = 0; c < 2; ++c)
      ap[c] = *reinterpret_cast<const bf16x8*>(&Plds[w][lr][c * 32 + lh * 8]);
#pragma unroll
    for (int c = 0; c < 2; ++c) {
      size_t vcol = (size_t)kt * 64 + c * 32 + lh * 8;
#pragma unroll
      for (int d = 0; d < 8; ++d) {
        bf16x8 bv = *reinterpret_cast<const bf16x8*>(Vbase + (size_t)(d * 16 + lr) * 4096 + vcol);
        acc_o[d] = __builtin_amdgcn_mfma_f32_16x16x32_bf16(ap[c], bv, acc_o[d], 0, 0, 0);
      }
    }
    asm volatile("" ::: "memory");
  }

  float inv[4] = {1.f / l_row[0], 1.f / l_row[1], 1.f / l_row[2], 1.f / l_row[3]};
#pragma unroll
  for (int d = 0; d < 8; ++d)
#pragma unroll
    for (int r = 0; r < 4; ++r) {
      size_t orow = (size_t)(b * 2048 + qt * 64 + w * 16 + lh * 4 + r) * 2048 + h * 128 + d * 16 + lr;
      Ob[orow] = f2bf(acc_o[d][r] * inv[r]);
    }
}

extern "C" void kernel_launch(void* const* d_in, const int* in_sizes, int n_in,
                              void* d_out, int out_size, void* d_ws, size_t ws_size,
                              hipStream_t stream) {
  const float* x  = (const float*)d_in[0];
  const float* rc = (const float*)d_in[1];
  const float* rs = (const float*)d_in[2];
  const float* Wq = (const float*)d_in[3];
  const float* Wk = (const float*)d_in[4];
  const float* Wv = (const float*)d_in[5];
  const float* Wo = (const float*)d_in[6];
  float* out = (float*)d_out;
  char* ws = (char*)d_ws;
  const size_t MB = 1024 * 1024;
  // layout (96 MB total); Ob reuses Wqb/Wkb slots (dead after their GEMMs)
  u16* xb  = (u16*)(ws);            // 16 MB
  u16* Wqb = (u16*)(ws + 16 * MB);  // 8 MB
  u16* Wkb = (u16*)(ws + 24 * MB);  // 8 MB
  u16* Wvb = (u16*)(ws + 32 * MB);  // 8 MB
  u16* Wob = (u16*)(ws + 40 * MB);  // 8 MB
  u16* Qb  = (u16*)(ws + 48 * MB);  // 16 MB
  u16* Kbf = (u16*)(ws + 64 * MB);  // 16 MB
  u16* VTb = (u16*)(ws + 80 * MB);  // 16 MB  [2048][4096]
  u16* Ob  = (u16*)(ws + 16 * MB);  // 16 MB (aliases Wqb+Wkb, safe by ordering)

  f32_to_bf16<<<2048, 256, 0, stream>>>(x, xb, 8388608);
  f32_to_bf16<<<1024, 256, 0, stream>>>(Wq, Wqb, 4194304);
  f32_to_bf16<<<1024, 256, 0, stream>>>(Wk, Wkb, 4194304);
  f32_to_bf16<<<1024, 256, 0, stream>>>(Wv, Wvb, 4194304);
  f32_to_bf16<<<1024, 256, 0, stream>>>(Wo, Wob, 4194304);

  gemm_bt<0><<<512, 256, 0, stream>>>(xb, Wqb, Qb, 4096, 2048, 2048);   // Q
  gemm_bt<0><<<512, 256, 0, stream>>>(xb, Wkb, Kbf, 4096, 2048, 2048);  // K
  gemm_bt<0><<<512, 256, 0, stream>>>(Wvb, xb, VTb, 2048, 4096, 2048);  // V^T (operands swapped)

  rope_kernel<<<4096, 256, 0, stream>>>(Qb, rc, rs);
  rope_kernel<<<4096, 256, 0, stream>>>(Kbf, rc, rs);

  attn_kernel<<<1024, 256, 0, stream>>>(Qb, Kbf, VTb, Ob);

  gemm_bt<1><<<512, 256, 0, stream>>>(Ob, Wob, (void*)out, 4096, 2048, 2048);  // out = O @ Wo^T (fp32)
}

// Round 2
// 381.904 us; speedup vs baseline: 1.9328x; 1.9328x over previous
//
#include <hip/hip_runtime.h>
#include <hip/hip_bf16.h>

typedef unsigned short u16;
typedef __bf16 bf16x8 __attribute__((ext_vector_type(8)));
typedef float f32x4 __attribute__((ext_vector_type(4)));

__device__ __forceinline__ float bf2f(u16 u) {
  union { unsigned int i; float f; } v; v.i = ((unsigned int)u) << 16; return v.f;
}
__device__ __forceinline__ u16 f2bf(float f) {
  union { float f; unsigned int i; } v; v.f = f;
  unsigned int r = v.i + 0x7fffu + ((v.i >> 16) & 1u);
  return (u16)(r >> 16);
}

__device__ __forceinline__ void async_load16(void* lds, const void* g) {
  __builtin_amdgcn_global_load_lds((const __attribute__((address_space(1))) void*)g,
                                   (__attribute__((address_space(3))) void*)lds, 16, 0, 0);
}

// ---------------- fp32 -> bf16 convert ----------------
__global__ void f32_to_bf16(const float* __restrict__ src, u16* __restrict__ dst, int n) {
  int idx = blockIdx.x * blockDim.x + threadIdx.x;
  int stride = gridDim.x * blockDim.x * 4;
  for (int i = idx * 4; i < n; i += stride) {
    float4 v = *(const float4*)(src + i);
    ushort4 o;
    o.x = f2bf(v.x); o.y = f2bf(v.y); o.z = f2bf(v.z); o.w = f2bf(v.w);
    *(ushort4*)(dst + i) = o;
  }
}

// ---------------- GEMM: C[M,N] = A[M,K] * B[N,K]^T (m97-style 128x128 tile) ----------------
template <int OUT_F32>
__global__ void gemm_bt(const u16* __restrict__ A, const u16* __restrict__ Bm,
                        void* __restrict__ C, int M, int N, int K) {
  __shared__ __align__(16) u16 sA[128 * 32];
  __shared__ __align__(16) u16 sB[128 * 32];
  const int nTn = N >> 7;
  const int nwg = gridDim.x;
  const int cpx = nwg >> 3;
  int id = blockIdx.x;
  int swz = (id & 7) * cpx + (id >> 3);   // XCD-chunked (nwg % 8 == 0)
  int tm = swz / nTn, tn = swz % nTn;
  const int t = threadIdx.x;
  const int w = t >> 6, l = t & 63;
  const int wr = w >> 1, wc = w & 1;
  const int lr = l & 15, lh = l >> 4;
  const size_t row0 = (size_t)tm * 128, col0 = (size_t)tn * 128;

  f32x4 zero = {0.f, 0.f, 0.f, 0.f};
  f32x4 acc[4][4];
#pragma unroll
  for (int i = 0; i < 4; ++i)
#pragma unroll
    for (int j = 0; j < 4; ++j) acc[i][j] = zero;

  const u16* Ag = A + row0 * K;
  const u16* Bg = Bm + col0 * K;

  for (int k0 = 0; k0 < K; k0 += 32) {
#pragma unroll
    for (int i = 0; i < 2; ++i) {
      int c = i * 256 + t;
      int r = c >> 2, kk = (c & 3) << 3;
      async_load16(sA + (((size_t)i * 256 + w * 64) << 3), Ag + (size_t)r * K + k0 + kk);
      async_load16(sB + (((size_t)i * 256 + w * 64) << 3), Bg + (size_t)r * K + k0 + kk);
    }
    __syncthreads();  // drains vmcnt: global_load_lds data landed
    bf16x8 af[4], bfr[4];
#pragma unroll
    for (int mi = 0; mi < 4; ++mi)
      af[mi] = *reinterpret_cast<const bf16x8*>(sA + (wr * 64 + mi * 16 + lr) * 32 + lh * 8);
#pragma unroll
    for (int ni = 0; ni < 4; ++ni)
      bfr[ni] = *reinterpret_cast<const bf16x8*>(sB + (wc * 64 + ni * 16 + lr) * 32 + lh * 8);
#pragma unroll
    for (int mi = 0; mi < 4; ++mi)
#pragma unroll
      for (int ni = 0; ni < 4; ++ni)
        acc[mi][ni] = __builtin_amdgcn_mfma_f32_16x16x32_bf16(af[mi], bfr[ni], acc[mi][ni], 0, 0, 0);
    __syncthreads();
  }

#pragma unroll
  for (int mi = 0; mi < 4; ++mi)
#pragma unroll
    for (int ni = 0; ni < 4; ++ni)
#pragma unroll
      for (int r = 0; r < 4; ++r) {
        size_t row = row0 + wr * 64 + mi * 16 + lh * 4 + r;
        size_t col = col0 + wc * 64 + ni * 16 + lr;
        float v = acc[mi][ni][r];
        if (OUT_F32)
          ((float*)C)[row * N + col] = v;
        else
          ((u16*)C)[row * N + col] = f2bf(v);
      }
}

// ---------------- RoPE (in-place on bf16 Q or K), [4096 rows][2048] ----------------
__global__ void rope_kernel(u16* __restrict__ q, const float* __restrict__ cosb,
                            const float* __restrict__ sinb) {
  int tid = blockIdx.x * blockDim.x + threadIdx.x;
  int p = tid & 15;
  int h = (tid >> 4) & 15;
  int row = tid >> 8;
  int s = row & 2047;
  int d0 = p << 2;
  size_t base = (size_t)row * 2048 + h * 128;
  u16* q0p = q + base + d0;
  u16* q1p = q + base + 64 + d0;
  ushort4 a = *(ushort4*)q0p, b = *(ushort4*)q1p;
  float4 c0 = *(const float4*)(cosb + s * 128 + d0);
  float4 c1 = *(const float4*)(cosb + s * 128 + 64 + d0);
  float4 s0 = *(const float4*)(sinb + s * 128 + d0);
  float4 s1 = *(const float4*)(sinb + s * 128 + 64 + d0);
  float a0 = bf2f(a.x), a1 = bf2f(a.y), a2 = bf2f(a.z), a3 = bf2f(a.w);
  float b0 = bf2f(b.x), b1 = bf2f(b.y), b2 = bf2f(b.z), b3 = bf2f(b.w);
  ushort4 o0, o1;
  o0.x = f2bf(a0 * c0.x - b0 * s0.x);
  o0.y = f2bf(a1 * c0.y - b1 * s0.y);
  o0.z = f2bf(a2 * c0.z - b2 * s0.z);
  o0.w = f2bf(a3 * c0.w - b3 * s0.w);
  o1.x = f2bf(b0 * c1.x + a0 * s1.x);
  o1.y = f2bf(b1 * c1.y + a1 * s1.y);
  o1.z = f2bf(b2 * c1.z + a2 * s1.z);
  o1.w = f2bf(b3 * c1.w + a3 * s1.w);
  *(ushort4*)q0p = o0;
  *(ushort4*)q1p = o1;
}

// ---------------- Flash attention (LDS-staged, double-buffered) ----------------
// Q,K: [B*S][2048] bf16 roped. VT: [2048][B*S] bf16. O: [B*S][2048] bf16.
// grid 512 = 32 bh * 16 qtiles(128 rows); block 256 = 4 waves * 32 q-rows.
// KV tile 64. LDS: K 2x16KB + V 2x16KB + P 16KB = 80KB -> 2 blocks/CU.
// All LDS tiles XOR-swizzled (byte ^= (row&7)<<4), applied via inverse-swizzled
// global source addresses for global_load_lds (rule 21: linear dest).
__global__ __launch_bounds__(256, 2)
void attn_kernel(const u16* __restrict__ Qb, const u16* __restrict__ Kb,
                 const u16* __restrict__ VT, u16* __restrict__ Ob) {
  __shared__ __align__(16) u16 sK[2][64 * 128];   // [seq 64][dh 128]
  __shared__ __align__(16) u16 sV[2][128 * 64];   // [dh 128][seq 64]
  __shared__ __align__(16) u16 sP[4][32 * 64];    // per-wave [q 32][k 64]

  int id = blockIdx.x;
  int swz = (id & 7) * 64 + (id >> 3);    // XCD-chunked: 4 heads per XCD -> KV L2-resident
  int bh = swz >> 4;
  int qb = swz & 15;
  int b = bh >> 4, h = bh & 15;
  int t = threadIdx.x, w = t >> 6, l = t & 63;
  int lr = l & 15, lh = l >> 4;
  int q0 = qb * 128;

  const u16* Kbase = Kb + (size_t)(b * 2048) * 2048 + h * 128;
  const u16* Vbase = VT + (size_t)(h * 128) * 4096 + b * 2048;

  // Q fragments: wave w owns rows q0 + w*32 .. +31 (2 frags of 16)
  bf16x8 aq[2][4];
#pragma unroll
  for (int qf = 0; qf < 2; ++qf) {
    size_t qrow = (size_t)(b * 2048 + q0 + w * 32 + qf * 16 + lr) * 2048 + h * 128;
#pragma unroll
    for (int c = 0; c < 4; ++c)
      aq[qf][c] = *reinterpret_cast<const bf16x8*>(Qb + qrow + c * 32 + lh * 8);
  }

  f32x4 zero = {0.f, 0.f, 0.f, 0.f};
  f32x4 acc_o[2][8];
#pragma unroll
  for (int qf = 0; qf < 2; ++qf)
#pragma unroll
    for (int d = 0; d < 8; ++d) acc_o[qf][d] = zero;
  float m_row[2][4], l_row[2][4];
#pragma unroll
  for (int qf = 0; qf < 2; ++qf)
#pragma unroll
    for (int r = 0; r < 4; ++r) { m_row[qf][r] = -1e30f; l_row[qf][r] = 0.f; }
  const float sc = 0.08838834764831845f;  // 1/sqrt(128)

  auto stage = [&](int buf, int kt2) {
    const u16* Kt = Kbase + (size_t)(kt2 * 64) * 2048;
    const u16* Vt = Vbase + kt2 * 64;
#pragma unroll
    for (int it = 0; it < 4; ++it) {
      int o = it * 4096 + t * 16;            // byte offset in 16KB tile
      int rowK = o >> 8;
      int cbK = (o & 255) ^ ((rowK & 7) << 4);
      async_load16((u16*)sK[buf] + (o >> 1), Kt + (size_t)rowK * 2048 + (cbK >> 1));
      int rowV = o >> 7;
      int cbV = (o & 127) ^ ((rowV & 7) << 4);
      async_load16((u16*)sV[buf] + (o >> 1), Vt + (size_t)rowV * 4096 + (cbV >> 1));
    }
  };

  stage(0, 0);
  __syncthreads();
  int cur = 0;

  for (int kt = 0; kt < 32; ++kt) {
    if (kt < 31) stage(cur ^ 1, kt + 1);

    const u16* sKc = sK[cur];
    const u16* sVc = sV[cur];

    // ---- QK^T: sacc[qf][g] over 64 k-cols ----
    f32x4 sacc[2][4];
#pragma unroll
    for (int qf = 0; qf < 2; ++qf)
#pragma unroll
      for (int g = 0; g < 4; ++g) sacc[qf][g] = zero;
#pragma unroll
    for (int g = 0; g < 4; ++g) {
      int row = g * 16 + lr;
      int xr = (lr & 7) << 4;
#pragma unroll
      for (int c = 0; c < 4; ++c) {
        int cb = (c * 64 + lh * 16) ^ xr;
        bf16x8 bk = *reinterpret_cast<const bf16x8*>(sKc + row * 128 + (cb >> 1));
        sacc[0][g] = __builtin_amdgcn_mfma_f32_16x16x32_bf16(aq[0][c], bk, sacc[0][g], 0, 0, 0);
        sacc[1][g] = __builtin_amdgcn_mfma_f32_16x16x32_bf16(aq[1][c], bk, sacc[1][g], 0, 0, 0);
      }
    }

    // ---- online softmax; q-row = qf*16 + lh*4 + r, reduce over 16 lr lanes ----
#pragma unroll
    for (int qf = 0; qf < 2; ++qf) {
#pragma unroll
      for (int r = 0; r < 4; ++r) {
        float mx = fmaxf(fmaxf(sacc[qf][0][r], sacc[qf][1][r]),
                         fmaxf(sacc[qf][2][r], sacc[qf][3][r]));
        mx *= sc;
#pragma unroll
        for (int msk = 1; msk < 16; msk <<= 1) mx = fmaxf(mx, __shfl_xor(mx, msk));
        float mn = fmaxf(m_row[qf][r], mx);
        float alpha = __expf(m_row[qf][r] - mn);
        m_row[qf][r] = mn;
        float rs = 0.f;
        int prow = qf * 16 + lh * 4 + r;
        int xw = (prow & 7) << 4;
#pragma unroll
        for (int g = 0; g < 4; ++g) {
          float e = __expf(sacc[qf][g][r] * sc - mn);
          rs += e;
          int cb = (g * 32 + lr * 2) ^ xw;
          sP[w][prow * 64 + (cb >> 1)] = f2bf(e);
        }
#pragma unroll
        for (int msk = 1; msk < 16; msk <<= 1) rs += __shfl_xor(rs, msk);
        l_row[qf][r] = l_row[qf][r] * alpha + rs;
        // rescale O accumulators for this row
#pragma unroll
        for (int d = 0; d < 8; ++d) acc_o[qf][d][r] *= alpha;
      }
    }

    // ---- PV: A = P from sP, B = V^T tile from sV ----
    bf16x8 ap[2][2];
#pragma unroll
    for (int qf = 0; qf < 2; ++qf) {
      int row = qf * 16 + lr;
      int xr = (lr & 7) << 4;
#pragma unroll
      for (int c = 0; c < 2; ++c) {
        int cb = (c * 64 + lh * 16) ^ xr;
        ap[qf][c] = *reinterpret_cast<const bf16x8*>(sP[w] + row * 64 + (cb >> 1));
      }
    }
#pragma unroll
    for (int c2 = 0; c2 < 2; ++c2) {
#pragma unroll
      for (int d = 0; d < 8; ++d) {
        int row = d * 16 + lr;
        int cb = (c2 * 64 + lh * 16) ^ ((lr & 7) << 4);
        bf16x8 bv = *reinterpret_cast<const bf16x8*>(sVc + row * 64 + (cb >> 1));
        acc_o[0][d] = __builtin_amdgcn_mfma_f32_16x16x32_bf16(ap[0][c2], bv, acc_o[0][d], 0, 0, 0);
        acc_o[1][d] = __builtin_amdgcn_mfma_f32_16x16x32_bf16(ap[1][c2], bv, acc_o[1][d], 0, 0, 0);
      }
    }

    __syncthreads();  // drains vmcnt(0)+lgkmcnt(0): next tile staged, cur fully consumed
    cur ^= 1;
  }

#pragma unroll
  for (int qf = 0; qf < 2; ++qf) {
    float inv[4];
#pragma unroll
    for (int r = 0; r < 4; ++r) inv[r] = 1.f / l_row[qf][r];
#pragma unroll
    for (int d = 0; d < 8; ++d)
#pragma unroll
      for (int r = 0; r < 4; ++r) {
        size_t orow = (size_t)(b * 2048 + q0 + w * 32 + qf * 16 + lh * 4 + r) * 2048
                      + h * 128 + d * 16 + lr;
        Ob[orow] = f2bf(acc_o[qf][d][r] * inv[r]);
      }
  }
}

extern "C" void kernel_launch(void* const* d_in, const int* in_sizes, int n_in,
                              void* d_out, int out_size, void* d_ws, size_t ws_size,
                              hipStream_t stream) {
  const float* x  = (const float*)d_in[0];
  const float* rc = (const float*)d_in[1];
  const float* rs = (const float*)d_in[2];
  const float* Wq = (const float*)d_in[3];
  const float* Wk = (const float*)d_in[4];
  const float* Wv = (const float*)d_in[5];
  const float* Wo = (const float*)d_in[6];
  float* out = (float*)d_out;
  char* ws = (char*)d_ws;
  const size_t MB = 1024 * 1024;
  u16* xb  = (u16*)(ws);            // 16 MB
  u16* Wqb = (u16*)(ws + 16 * MB);  // 8 MB
  u16* Wkb = (u16*)(ws + 24 * MB);  // 8 MB
  u16* Wvb = (u16*)(ws + 32 * MB);  // 8 MB
  u16* Wob = (u16*)(ws + 40 * MB);  // 8 MB
  u16* Qb  = (u16*)(ws + 48 * MB);  // 16 MB
  u16* Kbf = (u16*)(ws + 64 * MB);  // 16 MB
  u16* VTb = (u16*)(ws + 80 * MB);  // 16 MB  [2048][4096]
  u16* Ob  = (u16*)(ws + 16 * MB);  // 16 MB (aliases Wqb+Wkb, dead after their GEMMs)

  f32_to_bf16<<<2048, 256, 0, stream>>>(x, xb, 8388608);
  f32_to_bf16<<<1024, 256, 0, stream>>>(Wq, Wqb, 4194304);
  f32_to_bf16<<<1024, 256, 0, stream>>>(Wk, Wkb, 4194304);
  f32_to_bf16<<<1024, 256, 0, stream>>>(Wv, Wvb, 4194304);
  f32_to_bf16<<<1024, 256, 0, stream>>>(Wo, Wob, 4194304);

  gemm_bt<0><<<512, 256, 0, stream>>>(xb, Wqb, Qb, 4096, 2048, 2048);   // Q
  gemm_bt<0><<<512, 256, 0, stream>>>(xb, Wkb, Kbf, 4096, 2048, 2048);  // K
  gemm_bt<0><<<512, 256, 0, stream>>>(Wvb, xb, VTb, 2048, 4096, 2048);  // V^T (operands swapped)

  rope_kernel<<<4096, 256, 0, stream>>>(Qb, rc, rs);
  rope_kernel<<<4096, 256, 0, stream>>>(Kbf, rc, rs);

  attn_kernel<<<512, 256, 0, stream>>>(Qb, Kbf, VTb, Ob);

  gemm_bt<1><<<512, 256, 0, stream>>>(Ob, Wob, (void*)out, 4096, 2048, 2048);  // out = O @ Wo^T (fp32)
}

// Round 3
// 321.049 us; speedup vs baseline: 2.2992x; 1.1896x over previous
//
#include <hip/hip_runtime.h>
#include <hip/hip_bf16.h>

typedef unsigned short u16;
typedef __bf16 bf16x8 __attribute__((ext_vector_type(8)));
typedef float f32x4 __attribute__((ext_vector_type(4)));

__device__ __forceinline__ float bf2f(u16 u) {
  union { unsigned int i; float f; } v; v.i = ((unsigned int)u) << 16; return v.f;
}
__device__ __forceinline__ u16 f2bf(float f) {
  union { float f; unsigned int i; } v; v.f = f;
  unsigned int r = v.i + 0x7fffu + ((v.i >> 16) & 1u);
  return (u16)(r >> 16);
}
__device__ __forceinline__ unsigned cvtpk(float lo, float hi) {
  unsigned r;
  asm("v_cvt_pk_bf16_f32 %0, %1, %2" : "=v"(r) : "v"(lo), "v"(hi));
  return r;
}

__device__ __forceinline__ void async_load16(void* lds, const void* g) {
  __builtin_amdgcn_global_load_lds((const __attribute__((address_space(1))) void*)g,
                                   (__attribute__((address_space(3))) void*)lds, 16, 0, 0);
}

// ---------------- fp32 -> bf16 convert ----------------
__global__ void f32_to_bf16(const float* __restrict__ src, u16* __restrict__ dst, int n) {
  int idx = blockIdx.x * blockDim.x + threadIdx.x;
  int stride = gridDim.x * blockDim.x * 4;
  for (int i = idx * 4; i < n; i += stride) {
    float4 v = *(const float4*)(src + i);
    ushort4 o;
    o.x = f2bf(v.x); o.y = f2bf(v.y); o.z = f2bf(v.z); o.w = f2bf(v.w);
    *(ushort4*)(dst + i) = o;
  }
}

// ---------------- GEMM: C[M,N] = A[M,K] * B[N,K]^T (m97-style 128x128 tile) ----------------
template <int OUT_F32>
__global__ void gemm_bt(const u16* __restrict__ A, const u16* __restrict__ Bm,
                        void* __restrict__ C, int M, int N, int K) {
  __shared__ __align__(16) u16 sA[128 * 32];
  __shared__ __align__(16) u16 sB[128 * 32];
  const int nTn = N >> 7;
  const int nwg = gridDim.x;
  const int cpx = nwg >> 3;
  int id = blockIdx.x;
  int swz = (id & 7) * cpx + (id >> 3);   // XCD-chunked (nwg % 8 == 0)
  int tm = swz / nTn, tn = swz % nTn;
  const int t = threadIdx.x;
  const int w = t >> 6, l = t & 63;
  const int wr = w >> 1, wc = w & 1;
  const int lr = l & 15, lh = l >> 4;
  const size_t row0 = (size_t)tm * 128, col0 = (size_t)tn * 128;

  f32x4 zero = {0.f, 0.f, 0.f, 0.f};
  f32x4 acc[4][4];
#pragma unroll
  for (int i = 0; i < 4; ++i)
#pragma unroll
    for (int j = 0; j < 4; ++j) acc[i][j] = zero;

  const u16* Ag = A + row0 * K;
  const u16* Bg = Bm + col0 * K;

  for (int k0 = 0; k0 < K; k0 += 32) {
#pragma unroll
    for (int i = 0; i < 2; ++i) {
      int c = i * 256 + t;
      int r = c >> 2, kk = (c & 3) << 3;
      async_load16(sA + (((size_t)i * 256 + w * 64) << 3), Ag + (size_t)r * K + k0 + kk);
      async_load16(sB + (((size_t)i * 256 + w * 64) << 3), Bg + (size_t)r * K + k0 + kk);
    }
    __syncthreads();
    bf16x8 af[4], bfr[4];
#pragma unroll
    for (int mi = 0; mi < 4; ++mi)
      af[mi] = *reinterpret_cast<const bf16x8*>(sA + (wr * 64 + mi * 16 + lr) * 32 + lh * 8);
#pragma unroll
    for (int ni = 0; ni < 4; ++ni)
      bfr[ni] = *reinterpret_cast<const bf16x8*>(sB + (wc * 64 + ni * 16 + lr) * 32 + lh * 8);
#pragma unroll
    for (int mi = 0; mi < 4; ++mi)
#pragma unroll
      for (int ni = 0; ni < 4; ++ni)
        acc[mi][ni] = __builtin_amdgcn_mfma_f32_16x16x32_bf16(af[mi], bfr[ni], acc[mi][ni], 0, 0, 0);
    __syncthreads();
  }

#pragma unroll
  for (int mi = 0; mi < 4; ++mi)
#pragma unroll
    for (int ni = 0; ni < 4; ++ni)
#pragma unroll
      for (int r = 0; r < 4; ++r) {
        size_t row = row0 + wr * 64 + mi * 16 + lh * 4 + r;
        size_t col = col0 + wc * 64 + ni * 16 + lr;
        float v = acc[mi][ni][r];
        if (OUT_F32)
          ((float*)C)[row * N + col] = v;
        else
          ((u16*)C)[row * N + col] = f2bf(v);
      }
}

// ---------------- RoPE (in-place on bf16 Q or K), [4096 rows][2048], optional scale ----------------
__global__ void rope_kernel(u16* __restrict__ q, const float* __restrict__ cosb,
                            const float* __restrict__ sinb, float scale) {
  int tid = blockIdx.x * blockDim.x + threadIdx.x;
  int p = tid & 15;
  int h = (tid >> 4) & 15;
  int row = tid >> 8;
  int s = row & 2047;
  int d0 = p << 2;
  size_t base = (size_t)row * 2048 + h * 128;
  u16* q0p = q + base + d0;
  u16* q1p = q + base + 64 + d0;
  ushort4 a = *(ushort4*)q0p, b = *(ushort4*)q1p;
  float4 c0 = *(const float4*)(cosb + s * 128 + d0);
  float4 c1 = *(const float4*)(cosb + s * 128 + 64 + d0);
  float4 s0 = *(const float4*)(sinb + s * 128 + d0);
  float4 s1 = *(const float4*)(sinb + s * 128 + 64 + d0);
  float a0 = bf2f(a.x), a1 = bf2f(a.y), a2 = bf2f(a.z), a3 = bf2f(a.w);
  float b0 = bf2f(b.x), b1 = bf2f(b.y), b2 = bf2f(b.z), b3 = bf2f(b.w);
  ushort4 o0, o1;
  o0.x = f2bf((a0 * c0.x - b0 * s0.x) * scale);
  o0.y = f2bf((a1 * c0.y - b1 * s0.y) * scale);
  o0.z = f2bf((a2 * c0.z - b2 * s0.z) * scale);
  o0.w = f2bf((a3 * c0.w - b3 * s0.w) * scale);
  o1.x = f2bf((b0 * c1.x + a0 * s1.x) * scale);
  o1.y = f2bf((b1 * c1.y + a1 * s1.y) * scale);
  o1.z = f2bf((b2 * c1.z + a2 * s1.z) * scale);
  o1.w = f2bf((b3 * c1.w + a3 * s1.w) * scale);
  *(ushort4*)q0p = o0;
  *(ushort4*)q1p = o1;
}

// ---------------- Flash attention (swapped-operand, in-lane softmax) ----------------
// Q: [B*S][2048] bf16, roped AND pre-scaled by (1/sqrt(dh))*log2(e).
// K: [B*S][2048] bf16 roped. VT: [2048][B*S] bf16. O: [B*S][2048] bf16.
// grid 512 = 32 bh * 16 qtiles(128 rows); block 256 = 4 waves * 32 q-rows (2 qf of 16).
// Swapped QK^T: mfma(K,Q) -> S[k][q], q = lane&15 -> softmax is in-lane + 2 shfl.
// Swapped PV: mfma(VT,P) -> O^T[d][q]; alpha-rescale and normalize in-lane.
// LDS: K 2x16KB + V 2x16KB + P 4x4KB = 80KB -> 2 blocks/CU. All tiles XOR-swizzled
// (byte ^= (row&7)<<4); for global_load_lds the swizzle is on the global source.
__global__ __launch_bounds__(256, 2)
void attn_kernel(const u16* __restrict__ Qb, const u16* __restrict__ Kb,
                 const u16* __restrict__ VT, u16* __restrict__ Ob) {
  __shared__ __align__(16) u16 sK[2][64 * 128];   // [seq 64][dh 128]
  __shared__ __align__(16) u16 sV[2][128 * 64];   // [dh 128][seq 64]
  __shared__ __align__(16) u16 sP[4][32 * 64];    // per-wave P^T-store [q 32][k 64]

  int id = blockIdx.x;
  int swz = (id & 7) * 64 + (id >> 3);    // XCD-chunked: 4 heads per XCD -> KV L2-resident
  int bh = swz >> 4;
  int qb = swz & 15;
  int b = bh >> 4, h = bh & 15;
  int t = threadIdx.x, w = t >> 6, l = t & 63;
  int lr = l & 15, lh = l >> 4;
  int lr7 = lr & 7;
  int q0 = qb * 128;

  const u16* Kbase = Kb + (size_t)(b * 2048) * 2048 + h * 128;
  const u16* Vbase = VT + (size_t)(h * 128) * 4096 + b * 2048;
  u16* sPw = sP[w];

  // Q fragments (B-operand): wave w owns q rows q0 + w*32 + qf*16 + lr
  bf16x8 aq[2][4];
#pragma unroll
  for (int qf = 0; qf < 2; ++qf) {
    size_t qrow = (size_t)(b * 2048 + q0 + w * 32 + qf * 16 + lr) * 2048 + h * 128;
#pragma unroll
    for (int c = 0; c < 4; ++c)
      aq[qf][c] = *reinterpret_cast<const bf16x8*>(Qb + qrow + c * 32 + lh * 8);
  }

  f32x4 zero = {0.f, 0.f, 0.f, 0.f};
  f32x4 acc_o[2][8];  // O^T[d = dsub*16 + lh*4 + reg][q = lr]
#pragma unroll
  for (int qf = 0; qf < 2; ++qf)
#pragma unroll
    for (int d = 0; d < 8; ++d) acc_o[qf][d] = zero;
  float m_row[2] = {-1e30f, -1e30f};
  float l_row[2] = {0.f, 0.f};

  auto stage = [&](int buf, int kt2) {
    const u16* Kt = Kbase + (size_t)(kt2 * 64) * 2048;
    const u16* Vt = Vbase + kt2 * 64;
#pragma unroll
    for (int it = 0; it < 4; ++it) {
      int o = it * 4096 + t * 16;            // byte offset in 16KB tile
      int rowK = o >> 8;
      int cbK = (o & 255) ^ ((rowK & 7) << 4);
      async_load16((u16*)sK[buf] + (o >> 1), Kt + (size_t)rowK * 2048 + (cbK >> 1));
      int rowV = o >> 7;
      int cbV = (o & 127) ^ ((rowV & 7) << 4);
      async_load16((u16*)sV[buf] + (o >> 1), Vt + (size_t)rowV * 4096 + (cbV >> 1));
    }
  };

  stage(0, 0);
  __syncthreads();
  int cur = 0;

  for (int kt = 0; kt < 32; ++kt) {
    if (kt < 31) stage(cur ^ 1, kt + 1);

    const u16* sKc = sK[cur];
    const u16* sVc = sV[cur];

    // ---- QK^T swapped: sacc[qf][g] = S[k = g*16 + lh*4 + reg][q = lr] ----
    f32x4 sacc[2][4];
#pragma unroll
    for (int qf = 0; qf < 2; ++qf)
#pragma unroll
      for (int g = 0; g < 4; ++g) sacc[qf][g] = zero;
#pragma unroll
    for (int g = 0; g < 4; ++g) {
      int row = g * 16 + lr;
      int xr = lr7 << 4;
#pragma unroll
      for (int c = 0; c < 4; ++c) {
        int cb = (c * 64 + lh * 16) ^ xr;
        bf16x8 bk = *reinterpret_cast<const bf16x8*>(sKc + row * 128 + (cb >> 1));
        sacc[0][g] = __builtin_amdgcn_mfma_f32_16x16x32_bf16(bk, aq[0][c], sacc[0][g], 0, 0, 0);
        sacc[1][g] = __builtin_amdgcn_mfma_f32_16x16x32_bf16(bk, aq[1][c], sacc[1][g], 0, 0, 0);
      }
    }

    // ---- in-lane online softmax over k (q = lr is lane-local) ----
#pragma unroll
    for (int qf = 0; qf < 2; ++qf) {
      // max of 16 in-lane values (tree) then reduce across 4 lh-groups
      f32x4 m4;
#pragma unroll
      for (int e = 0; e < 4; ++e)
        m4[e] = fmaxf(fmaxf(sacc[qf][0][e], sacc[qf][1][e]),
                      fmaxf(sacc[qf][2][e], sacc[qf][3][e]));
      float mx = fmaxf(fmaxf(m4[0], m4[1]), fmaxf(m4[2], m4[3]));
      mx = fmaxf(mx, __shfl_xor(mx, 16));
      mx = fmaxf(mx, __shfl_xor(mx, 32));
      float mo = m_row[qf];
      if (!__all(mx <= mo + 8.f)) {     // T13 defer-max (exp2 space, P <= 2^8)
        float mn = fmaxf(mo, mx);
        float al = __builtin_amdgcn_exp2f(mo - mn);
        m_row[qf] = mn;
        l_row[qf] *= al;
#pragma unroll
        for (int d = 0; d < 8; ++d) acc_o[qf][d] *= al;
      }
      float mn = m_row[qf];
#pragma unroll
      for (int g = 0; g < 4; ++g)
#pragma unroll
        for (int e = 0; e < 4; ++e)
          sacc[qf][g][e] = __builtin_amdgcn_exp2f(sacc[qf][g][e] - mn);
      f32x4 s4;
#pragma unroll
      for (int e = 0; e < 4; ++e)
        s4[e] = (sacc[qf][0][e] + sacc[qf][1][e]) + (sacc[qf][2][e] + sacc[qf][3][e]);
      float rs = (s4[0] + s4[1]) + (s4[2] + s4[3]);
      rs += __shfl_xor(rs, 16);
      rs += __shfl_xor(rs, 32);
      l_row[qf] += rs;

      // pack P to bf16 pairs, write P^T-store rows: sP[q=lr][k], swizzled
      int rowb = (qf * 16 + lr) * 128;
      int xw = lr7 << 4;
#pragma unroll
      for (int g = 0; g < 4; ++g) {
        uint2 pw;
        pw.x = cvtpk(sacc[qf][g][0], sacc[qf][g][1]);
        pw.y = cvtpk(sacc[qf][g][2], sacc[qf][g][3]);
        int cb = (g * 32 + lh * 8) ^ xw;
        *reinterpret_cast<uint2*>(reinterpret_cast<char*>(sPw) + rowb + cb) = pw;
      }
    }

    // ---- PV swapped: acc_o[qf][dsub] += VT_tile * P ----
    bf16x8 bp[2][2];
#pragma unroll
    for (int qf = 0; qf < 2; ++qf) {
      int rowb = (qf * 16 + lr) * 128;
      int xr = lr7 << 4;
#pragma unroll
      for (int c2 = 0; c2 < 2; ++c2) {
        int cb = (c2 * 64 + lh * 16) ^ xr;
        bp[qf][c2] = *reinterpret_cast<const bf16x8*>(
            reinterpret_cast<const char*>(sPw) + rowb + cb);
      }
    }
#pragma unroll
    for (int c2 = 0; c2 < 2; ++c2) {
#pragma unroll
      for (int d = 0; d < 8; ++d) {
        int row = d * 16 + lr;
        int cb = (c2 * 64 + lh * 16) ^ (lr7 << 4);
        bf16x8 bv = *reinterpret_cast<const bf16x8*>(sVc + row * 64 + (cb >> 1));
        acc_o[0][d] = __builtin_amdgcn_mfma_f32_16x16x32_bf16(bv, bp[0][c2], acc_o[0][d], 0, 0, 0);
        acc_o[1][d] = __builtin_amdgcn_mfma_f32_16x16x32_bf16(bv, bp[1][c2], acc_o[1][d], 0, 0, 0);
      }
    }

    __syncthreads();  // next tile staged; cur fully consumed
    cur ^= 1;
  }

  // ---- epilogue: normalize (in-lane), store O[q][d] as ushort4 ----
#pragma unroll
  for (int qf = 0; qf < 2; ++qf) {
    float inv = 1.f / l_row[qf];
    size_t qrow = (size_t)(b * 2048 + q0 + w * 32 + qf * 16 + lr) * 2048 + h * 128;
#pragma unroll
    for (int d = 0; d < 8; ++d) {
      ushort4 o;
      o.x = f2bf(acc_o[qf][d][0] * inv);
      o.y = f2bf(acc_o[qf][d][1] * inv);
      o.z = f2bf(acc_o[qf][d][2] * inv);
      o.w = f2bf(acc_o[qf][d][3] * inv);
      *reinterpret_cast<ushort4*>(Ob + qrow + d * 16 + lh * 4) = o;
    }
  }
}

extern "C" void kernel_launch(void* const* d_in, const int* in_sizes, int n_in,
                              void* d_out, int out_size, void* d_ws, size_t ws_size,
                              hipStream_t stream) {
  const float* x  = (const float*)d_in[0];
  const float* rc = (const float*)d_in[1];
  const float* rs = (const float*)d_in[2];
  const float* Wq = (const float*)d_in[3];
  const float* Wk = (const float*)d_in[4];
  const float* Wv = (const float*)d_in[5];
  const float* Wo = (const float*)d_in[6];
  float* out = (float*)d_out;
  char* ws = (char*)d_ws;
  const size_t MB = 1024 * 1024;
  u16* xb  = (u16*)(ws);            // 16 MB
  u16* Wqb = (u16*)(ws + 16 * MB);  // 8 MB
  u16* Wkb = (u16*)(ws + 24 * MB);  // 8 MB
  u16* Wvb = (u16*)(ws + 32 * MB);  // 8 MB
  u16* Wob = (u16*)(ws + 40 * MB);  // 8 MB
  u16* Qb  = (u16*)(ws + 48 * MB);  // 16 MB
  u16* Kbf = (u16*)(ws + 64 * MB);  // 16 MB
  u16* VTb = (u16*)(ws + 80 * MB);  // 16 MB  [2048][4096]
  u16* Ob  = (u16*)(ws + 16 * MB);  // 16 MB (aliases Wqb+Wkb, dead after their GEMMs)

  f32_to_bf16<<<2048, 256, 0, stream>>>(x, xb, 8388608);
  f32_to_bf16<<<1024, 256, 0, stream>>>(Wq, Wqb, 4194304);
  f32_to_bf16<<<1024, 256, 0, stream>>>(Wk, Wkb, 4194304);
  f32_to_bf16<<<1024, 256, 0, stream>>>(Wv, Wvb, 4194304);
  f32_to_bf16<<<1024, 256, 0, stream>>>(Wo, Wob, 4194304);

  gemm_bt<0><<<512, 256, 0, stream>>>(xb, Wqb, Qb, 4096, 2048, 2048);   // Q
  gemm_bt<0><<<512, 256, 0, stream>>>(xb, Wkb, Kbf, 4096, 2048, 2048);  // K
  gemm_bt<0><<<512, 256, 0, stream>>>(Wvb, xb, VTb, 2048, 4096, 2048);  // V^T (operands swapped)

  // Q gets (1/sqrt(dh)) * log2(e) folded in; attention uses exp2.
  const float qscale = 0.08838834764831845f * 1.4426950408889634f;
  rope_kernel<<<4096, 256, 0, stream>>>(Qb, rc, rs, qscale);
  rope_kernel<<<4096, 256, 0, stream>>>(Kbf, rc, rs, 1.0f);

  attn_kernel<<<512, 256, 0, stream>>>(Qb, Kbf, VTb, Ob);

  gemm_bt<1><<<512, 256, 0, stream>>>(Ob, Wob, (void*)out, 4096, 2048, 2048);  // out = O @ Wo^T (fp32)
}